// Round 1
// baseline (284.555 us; speedup 1.0000x reference)
//
#include <hip/hip_runtime.h>

#define C2 0.17677669529663687f  // 1/(4*sqrt(2))

typedef __attribute__((ext_vector_type(8))) short short8;
typedef __attribute__((ext_vector_type(8))) unsigned short ushort8;
typedef __attribute__((ext_vector_type(4))) float f32x4;

// fp32 -> bf16 round-to-nearest-even
__device__ __forceinline__ unsigned short f2bf(float x) {
    union { float f; unsigned u; } v; v.f = x;
    unsigned r = v.u + 0x7fffu + ((v.u >> 16) & 1u);
    return (unsigned short)(r >> 16);
}
__device__ __forceinline__ float bf2f(unsigned short u) {
    union { unsigned u; float f; } v; v.u = ((unsigned)u) << 16;
    return v.f;
}

// ---------------- shared-memory union: one 107 KB pool, 3 phase layouts ----------------
struct SplitKSm {
    unsigned short Al[2][2][64][40];
    unsigned short Bl[2][2][64][40];
    float red[64][65];
};
struct StateSm {
    float Kc[64][17];
    unsigned short Pk[320][72];
    unsigned short Vt[80][72];
};
struct OutSm {
    float Qc[64][17];
    unsigned short Aq[64][40];
    unsigned short Kb[64][40];
    unsigned short Pq[64][360];
    unsigned short Sv[64][360];
    float zl[288];
    float dpart[6][64];
};
union __align__(16) SmemU { SplitKSm g; StateSm a; OutSm c; };
// sizeof(SmemU) = 109,440 B -> 1 block/CU, grid 192 <= 256 CUs => co-residency guaranteed.

// ---------------- device-scope grid barrier (sense via generation counter) ----------------
// bar[0] = arrival counter, bar[1] = generation. Init to 0 by hipMemsetAsync each launch
// (workspace is re-poisoned between iterations, so no residual-state assumptions).
__device__ __forceinline__ void grid_sync(int* bar, int nblk) {
    __syncthreads();
    if (threadIdx.x == 0) {
        __threadfence();   // agent-scope release: dirty L2 lines written back (cross-XCD visibility)
        int gen = __hip_atomic_load(&bar[1], __ATOMIC_RELAXED, __HIP_MEMORY_SCOPE_AGENT);
        int arr = __hip_atomic_fetch_add(&bar[0], 1, __ATOMIC_ACQ_REL, __HIP_MEMORY_SCOPE_AGENT);
        if (arr == nblk - 1) {
            __hip_atomic_store(&bar[0], 0, __ATOMIC_RELAXED, __HIP_MEMORY_SCOPE_AGENT);
            __hip_atomic_store(&bar[1], gen + 1, __ATOMIC_RELEASE, __HIP_MEMORY_SCOPE_AGENT);
        } else {
            int cur;
            do {
                __builtin_amdgcn_s_sleep(2);
                cur = __hip_atomic_load(&bar[1], __ATOMIC_ACQUIRE, __HIP_MEMORY_SCOPE_AGENT);
            } while (cur == gen);
        }
        __threadfence();   // acquire side: invalidate L1/L2 so post-barrier reads are fresh
    }
    __syncthreads();
}

// ---------------- in-block split-K MFMA GEMM (verbatim from 5-kernel version) ----------------
// 512 threads: group g = waves 0-3 / 4-7 each computes the same 64x64 tile over half of K
// (K=768 -> 2x384, 12 BK=32 steps, register-prefetch double-buffered LDS, one barrier/step),
// then group 1 dumps its partial to LDS and group 0 adds + stores.
__device__ void gemm_inblk_splitk(
    SplitKSm& smem, const float* __restrict__ A, const float* __restrict__ W,
    float* __restrict__ out, int row0, int n0, int outcol0, int ldw, int outld)
{
    const int tid = threadIdx.x;            // 0..511
    const int g = tid >> 8;                 // K-group
    const int t = tid & 255;
    const int lane = t & 63, wave4 = t >> 6;
    const int wm = wave4 & 1, wn = wave4 >> 1;
    const int quad = lane >> 4, lr = lane & 15;
    const int k0base = g * 384;

    f32x4 acc[2][2] = {{{0.f,0.f,0.f,0.f},{0.f,0.f,0.f,0.f}},
                       {{0.f,0.f,0.f,0.f},{0.f,0.f,0.f,0.f}}};

    float4 ra[2], rb[2];
    #pragma unroll
    for (int l = 0; l < 2; ++l) {
        int idx = t + l * 256;
        ra[l] = *(const float4*)&A[(size_t)(row0 + (idx >> 3)) * 768 + k0base + (idx & 7) * 4];
        rb[l] = *(const float4*)&W[(size_t)(k0base + (idx >> 4)) * ldw + n0 + (idx & 15) * 4];
    }
    #pragma unroll
    for (int l = 0; l < 2; ++l) {
        int idx = t + l * 256;
        *(ushort4*)&smem.Al[g][0][idx >> 3][(idx & 7) * 4] =
            make_ushort4(f2bf(ra[l].x), f2bf(ra[l].y), f2bf(ra[l].z), f2bf(ra[l].w));
        int kr = idx >> 4, nq = (idx & 15) * 4;
        int col = (((kr >> 3) ^ ((idx & 15) >> 2)) << 3) | (kr & 7);
        smem.Bl[g][0][nq + 0][col] = f2bf(rb[l].x);
        smem.Bl[g][0][nq + 1][col] = f2bf(rb[l].y);
        smem.Bl[g][0][nq + 2][col] = f2bf(rb[l].z);
        smem.Bl[g][0][nq + 3][col] = f2bf(rb[l].w);
    }
    __syncthreads();

    const int ITER = 12;   // 384 / 32
    #pragma unroll
    for (int i = 0; i < ITER; ++i) {
        const int cur = i & 1, nxt = cur ^ 1;
        float4 na[2], nb[2];
        if (i + 1 < ITER) {
            int kn = k0base + (i + 1) * 32;
            #pragma unroll
            for (int l = 0; l < 2; ++l) {
                int idx = t + l * 256;
                na[l] = *(const float4*)&A[(size_t)(row0 + (idx >> 3)) * 768 + kn + (idx & 7) * 4];
                nb[l] = *(const float4*)&W[(size_t)(kn + (idx >> 4)) * ldw + n0 + (idx & 15) * 4];
            }
        }
        short8 af[2], bfr[2];
        #pragma unroll
        for (int mi = 0; mi < 2; ++mi)
            af[mi] = *(const short8*)&smem.Al[g][cur][wm * 32 + mi * 16 + lr][quad << 3];
        #pragma unroll
        for (int ni = 0; ni < 2; ++ni) {
            int csw = quad ^ ((wn * 2 + ni) & 3);
            bfr[ni] = *(const short8*)&smem.Bl[g][cur][wn * 32 + ni * 16 + lr][csw << 3];
        }
        #pragma unroll
        for (int mi = 0; mi < 2; ++mi)
            #pragma unroll
            for (int ni = 0; ni < 2; ++ni)
                acc[mi][ni] = __builtin_amdgcn_mfma_f32_16x16x32_bf16(af[mi], bfr[ni], acc[mi][ni], 0, 0, 0);
        if (i + 1 < ITER) {
            #pragma unroll
            for (int l = 0; l < 2; ++l) {
                int idx = t + l * 256;
                *(ushort4*)&smem.Al[g][nxt][idx >> 3][(idx & 7) * 4] =
                    make_ushort4(f2bf(na[l].x), f2bf(na[l].y), f2bf(na[l].z), f2bf(na[l].w));
                int kr = idx >> 4, nq = (idx & 15) * 4;
                int col = (((kr >> 3) ^ ((idx & 15) >> 2)) << 3) | (kr & 7);
                smem.Bl[g][nxt][nq + 0][col] = f2bf(nb[l].x);
                smem.Bl[g][nxt][nq + 1][col] = f2bf(nb[l].y);
                smem.Bl[g][nxt][nq + 2][col] = f2bf(nb[l].z);
                smem.Bl[g][nxt][nq + 3][col] = f2bf(nb[l].w);
            }
        }
        __syncthreads();
    }
    if (g == 1) {
        #pragma unroll
        for (int mi = 0; mi < 2; ++mi)
            #pragma unroll
            for (int ni = 0; ni < 2; ++ni)
                #pragma unroll
                for (int r = 0; r < 4; ++r)
                    smem.red[wm * 32 + mi * 16 + quad * 4 + r][wn * 32 + ni * 16 + lr] = acc[mi][ni][r];
    }
    __syncthreads();
    if (g == 0) {
        #pragma unroll
        for (int mi = 0; mi < 2; ++mi)
            #pragma unroll
            for (int ni = 0; ni < 2; ++ni)
                #pragma unroll
                for (int r = 0; r < 4; ++r) {
                    int rr = wm * 32 + mi * 16 + quad * 4 + r;
                    int cc = wn * 32 + ni * 16 + lr;
                    out[(size_t)(row0 + rr) * outld + outcol0 + cc] = acc[mi][ni][r] + smem.red[rr][cc];
                }
    }
}

// ===================== ONE persistent kernel: all 5 phases =====================
// grid 192 x 512 threads. 1 block/CU (LDS-limited) -> all blocks co-resident -> grid_sync safe.
__global__ __launch_bounds__(512) void based_mega(
    const float* __restrict__ hs, const float* __restrict__ Wq, const float* __restrict__ Wk,
    const float* __restrict__ Wv, const float* __restrict__ Wo, float* __restrict__ out,
    float* __restrict__ qkv, float* __restrict__ yb, unsigned short* __restrict__ St,
    float* __restrict__ zb, int* __restrict__ bar)
{
    __shared__ SmemU sm;
    const int b = blockIdx.x;
    const int tid = threadIdx.x;

    // ---------- Phase 0: qkv = hidden @ [Wq|Wk|Wv], 288 64x64 tiles grid-strided ----------
    {
        const int ntiles = (b < 96) ? 2 : 1;
        for (int ti = 0; ti < ntiles; ++ti) {
            int tl = b + ti * 192;
            int mt = tl / 18, nt = tl % 18;
            const float* W; int ldw, n0;
            if (nt < 3)      { W = Wq; ldw = 192; n0 = nt * 64; }
            else if (nt < 6) { W = Wk; ldw = 192; n0 = (nt - 3) * 64; }
            else             { W = Wv; ldw = 768; n0 = (nt - 6) * 64; }
            gemm_inblk_splitk(sm.g, hs, W, qkv, mt * 64, n0, nt * 64, ldw, 1152);
        }
    }
    grid_sync(bar, 192);

    const int c = b & 15, h = b >> 4;   // (chunk, head) for phases A and C

    // ---------- Phase A: per-chunk state S_T (bf16) + z via MFMA ----------
    {
        if (tid < 256) {
            int s = tid >> 2, f4 = (tid & 3) * 4;
            float4 kv = *(const float4*)&qkv[(size_t)(c * 64 + s) * 1152 + 192 + h * 16 + f4];
            sm.a.Kc[s][f4 + 0] = kv.x; sm.a.Kc[s][f4 + 1] = kv.y;
            sm.a.Kc[s][f4 + 2] = kv.z; sm.a.Kc[s][f4 + 3] = kv.w;
        }
        #pragma unroll
        for (int l = 0; l < 2; ++l) {
            int idx = tid + l * 512;
            int s = idx >> 4, d4 = (idx & 15) * 4;
            float4 vv = *(const float4*)&qkv[(size_t)(c * 64 + s) * 1152 + 384 + h * 64 + d4];
            sm.a.Vt[d4 + 0][s] = f2bf(vv.x);
            sm.a.Vt[d4 + 1][s] = f2bf(vv.y);
            sm.a.Vt[d4 + 2][s] = f2bf(vv.z);
            sm.a.Vt[d4 + 3][s] = f2bf(vv.w);
        }
        for (int idx = tid; idx < 16 * 72; idx += 512) {
            int rr = 64 + idx / 72, ss = idx % 72;
            sm.a.Vt[rr][ss] = (rr == 64 && ss < 64) ? (unsigned short)0x3F80 : (unsigned short)0;
        }
        __syncthreads();
        for (int idx = tid; idx < 2880; idx += 512) {
            int n = idx / 9, s8 = (idx % 9) * 8;
            short8 v8;
            #pragma unroll
            for (int tt = 0; tt < 8; ++tt) {
                int s = s8 + tt;
                float ph = 0.f;
                if (s < 64 && n < 273) {
                    if (n == 0) ph = 1.f;
                    else if (n < 17) ph = sm.a.Kc[s][n - 1] * 0.5f;
                    else { int m = n - 17; ph = sm.a.Kc[s][m >> 4] * sm.a.Kc[s][m & 15] * C2; }
                }
                v8[tt] = (short)f2bf(ph);
            }
            *(short8*)&sm.a.Pk[n][s8] = v8;
        }
        __syncthreads();

        // 20 feature n-tiles redistributed over 8 waves: wave w owns tiles w, w+8, w+16(<20)
        const int lane = tid & 63, wave = tid >> 6;
        const int quad = lane >> 4, lr = lane & 15;
        f32x4 acc[5][3];
        #pragma unroll
        for (int mt = 0; mt < 5; ++mt)
            #pragma unroll
            for (int nt = 0; nt < 3; ++nt) acc[mt][nt] = (f32x4){0.f, 0.f, 0.f, 0.f};
        #pragma unroll
        for (int ks = 0; ks < 2; ++ks) {
            short8 af[5], bfr[3];
            #pragma unroll
            for (int mt = 0; mt < 5; ++mt)
                af[mt] = *(const short8*)&sm.a.Vt[mt * 16 + lr][ks * 32 + quad * 8];
            #pragma unroll
            for (int nt = 0; nt < 3; ++nt)
                if (wave + 8 * nt < 20)
                    bfr[nt] = *(const short8*)&sm.a.Pk[(wave + 8 * nt) * 16 + lr][ks * 32 + quad * 8];
            #pragma unroll
            for (int mt = 0; mt < 5; ++mt)
                #pragma unroll
                for (int nt = 0; nt < 3; ++nt)
                    if (wave + 8 * nt < 20)
                        acc[mt][nt] = __builtin_amdgcn_mfma_f32_16x16x32_bf16(af[mt], bfr[nt], acc[mt][nt], 0, 0, 0);
        }
        unsigned short* Sbt = St + (size_t)(h * 16 + c) * 18432;
        float* zp = zb + (h * 16 + c) * 273;
        #pragma unroll
        for (int nt = 0; nt < 3; ++nt) {
            if (wave + 8 * nt < 20) {
                int n = (wave + 8 * nt) * 16 + lr;
                if (n < 273) {
                    #pragma unroll
                    for (int mt = 0; mt < 4; ++mt)
                        #pragma unroll
                        for (int r = 0; r < 4; ++r)
                            Sbt[(mt * 16 + quad * 4 + r) * 288 + n] = f2bf(acc[mt][nt][r]);
                    if (quad == 0) zp[n] = acc[4][nt][0];   // d==64 ones-row -> z
                }
            }
        }
    }
    grid_sync(bar, 192);

    // ---------- Phase B: exclusive prefix over 16 chunks, batched loads (no dep chain) ----------
    {
        int gid = b * 512 + tid;
        const int NV = 12 * 64 * 36;   // ushort8 chains over all 288 cols (pads harmless)
        if (gid < NV) {
            int hh = gid / (64 * 36), rem = gid % (64 * 36);
            int d = rem / 36, nb = rem % 36;
            unsigned short* p = St + (size_t)hh * 16 * 18432 + d * 288 + nb * 8;
            ushort8 v[16];
            #pragma unroll
            for (int cc = 0; cc < 16; ++cc) v[cc] = *(const ushort8*)(p + (size_t)cc * 18432);
            float run[8] = {0.f,0.f,0.f,0.f,0.f,0.f,0.f,0.f};
            #pragma unroll
            for (int cc = 0; cc < 16; ++cc) {
                ushort8 w;
                #pragma unroll
                for (int j = 0; j < 8; ++j) {
                    w[j] = f2bf(run[j]);
                    run[j] += bf2f(v[cc][j]);
                }
                *(ushort8*)(p + (size_t)cc * 18432) = w;
            }
        } else if (gid < NV + 12 * 273) {
            int e2 = gid - NV, hh = e2 / 273, n = e2 % 273;
            float* p = zb + hh * 16 * 273 + n;
            float v[16];
            #pragma unroll
            for (int cc = 0; cc < 16; ++cc) v[cc] = p[cc * 273];
            float run = 0.f;
            #pragma unroll
            for (int cc = 0; cc < 16; ++cc) { p[cc * 273] = run; run += v[cc]; }
        }
    }
    grid_sync(bar, 192);

    // ---------- Phase C: per-chunk output (original 256-thread body, barriers hoisted) ----------
    {
        const int lane = tid & 63, wave = tid >> 6;     // wave < 4 when tid < 256
        const int wm = wave & 1, wn = wave >> 1;
        const int quad = lane >> 4, lr = lane & 15;

        if (tid < 256) {
            int s = tid >> 2, f4 = (tid & 3) * 4;
            const float* base = &qkv[(size_t)(c * 64 + s) * 1152 + h * 16];
            float4 qv = *(const float4*)&base[f4];
            float4 kv = *(const float4*)&base[192 + f4];
            sm.c.Qc[s][f4 + 0] = qv.x; sm.c.Qc[s][f4 + 1] = qv.y;
            sm.c.Qc[s][f4 + 2] = qv.z; sm.c.Qc[s][f4 + 3] = qv.w;
            *(ushort4*)&sm.c.Aq[s][f4] = make_ushort4(f2bf(qv.x), f2bf(qv.y), f2bf(qv.z), f2bf(qv.w));
            *(ushort4*)&sm.c.Kb[s][f4] = make_ushort4(f2bf(kv.x), f2bf(kv.y), f2bf(kv.z), f2bf(kv.w));
            *(ushort4*)&sm.c.Aq[s][16 + (tid & 3) * 4] = make_ushort4(0, 0, 0, 0);
            *(ushort4*)&sm.c.Kb[s][16 + (tid & 3) * 4] = make_ushort4(0, 0, 0, 0);
            #pragma unroll
            for (int l = 0; l < 4; ++l) {                    // V -> Sv cols 288..351
                int idx = tid + l * 256;
                int ss = idx >> 4, d4 = (idx & 15) * 4;
                float4 vv = *(const float4*)&qkv[(size_t)(c * 64 + ss) * 1152 + 384 + h * 64 + d4];
                sm.c.Sv[d4 + 0][288 + ss] = f2bf(vv.x);
                sm.c.Sv[d4 + 1][288 + ss] = f2bf(vv.y);
                sm.c.Sv[d4 + 2][288 + ss] = f2bf(vv.z);
                sm.c.Sv[d4 + 3][288 + ss] = f2bf(vv.w);
            }
            const unsigned short* Sgt = St + (size_t)(h * 16 + c) * 18432;
            for (int idx = tid; idx < 64 * 34; idx += 256) {       // n 0..271
                int d = idx / 34, n8 = (idx % 34) * 8;
                *(ushort8*)&sm.c.Sv[d][n8] = *(const ushort8*)&Sgt[d * 288 + n8];
            }
            for (int idx = tid; idx < 64; idx += 256) sm.c.Sv[idx][272] = Sgt[idx * 288 + 272];
            for (int idx = tid; idx < 64 * 15; idx += 256) {       // zero n 273..287
                int d = idx / 15, n = 273 + idx % 15;
                sm.c.Sv[d][n] = 0;
            }
            const float* zg = zb + (h * 16 + c) * 273;
            for (int idx = tid; idx < 288; idx += 256) sm.c.zl[idx] = (idx < 273) ? zg[idx] : 0.f;
        }
        __syncthreads();

        if (tid < 256) {
            f32x4 accS[2][2] = {{{0.f,0.f,0.f,0.f},{0.f,0.f,0.f,0.f}},
                                {{0.f,0.f,0.f,0.f},{0.f,0.f,0.f,0.f}}};
            {
                short8 af[2], bfr[2];
                #pragma unroll
                for (int mi = 0; mi < 2; ++mi)
                    af[mi] = *(const short8*)&sm.c.Aq[wm * 32 + mi * 16 + lr][quad * 8];
                #pragma unroll
                for (int ni = 0; ni < 2; ++ni)
                    bfr[ni] = *(const short8*)&sm.c.Kb[wn * 32 + ni * 16 + lr][quad * 8];
                #pragma unroll
                for (int mi = 0; mi < 2; ++mi)
                    #pragma unroll
                    for (int ni = 0; ni < 2; ++ni)
                        accS[mi][ni] = __builtin_amdgcn_mfma_f32_16x16x32_bf16(af[mi], bfr[ni], accS[mi][ni], 0, 0, 0);
            }
            {
                int i = lane;
                float qr[16];
                #pragma unroll
                for (int f = 0; f < 16; ++f) qr[f] = sm.c.Qc[i][f];
                float dp = 0.f;
                int n0 = wave * 72;
                for (int n = n0; n < n0 + 72; ++n) {
                    float ph;
                    if (n == 0) ph = 1.f;
                    else if (n < 17) ph = qr[n - 1] * 0.5f;
                    else if (n < 273) { int m = n - 17; ph = qr[m >> 4] * qr[m & 15] * C2; }
                    else ph = 0.f;
                    sm.c.Pq[i][n] = f2bf(ph);
                    dp += ph * sm.c.zl[n];
                }
                sm.c.dpart[wave][i] = dp;
            }
            #pragma unroll
            for (int mi = 0; mi < 2; ++mi) {
                float rs[4] = {0.f, 0.f, 0.f, 0.f};
                #pragma unroll
                for (int ni = 0; ni < 2; ++ni)
                    #pragma unroll
                    for (int r = 0; r < 4; ++r) {
                        int i = wm * 32 + mi * 16 + quad * 4 + r;
                        int j = wn * 32 + ni * 16 + lr;
                        float u = accS[mi][ni][r];
                        float sc = (j <= i) ? (1.f + 0.25f * u + u * u * (1.f / 32.f)) : 0.f;
                        rs[r] += sc;
                        sm.c.Pq[i][288 + j] = f2bf(sc);
                    }
                #pragma unroll
                for (int r = 0; r < 4; ++r) {
                    float v = rs[r];
                    v += __shfl_xor(v, 1);
                    v += __shfl_xor(v, 2);
                    v += __shfl_xor(v, 4);
                    v += __shfl_xor(v, 8);
                    if (lr == 0) sm.c.dpart[4 + wn][wm * 32 + mi * 16 + quad * 4 + r] = v;
                }
            }
        }
        __syncthreads();

        if (tid < 256) {
            f32x4 acc[2][2] = {{{0.f,0.f,0.f,0.f},{0.f,0.f,0.f,0.f}},
                               {{0.f,0.f,0.f,0.f},{0.f,0.f,0.f,0.f}}};
            #pragma unroll
            for (int ks = 0; ks < 11; ++ks) {
                short8 af[2], bfr[2];
                #pragma unroll
                for (int mi = 0; mi < 2; ++mi)
                    af[mi] = *(const short8*)&sm.c.Pq[wm * 32 + mi * 16 + lr][ks * 32 + quad * 8];
                #pragma unroll
                for (int ni = 0; ni < 2; ++ni)
                    bfr[ni] = *(const short8*)&sm.c.Sv[wn * 32 + ni * 16 + lr][ks * 32 + quad * 8];
                #pragma unroll
                for (int mi = 0; mi < 2; ++mi)
                    #pragma unroll
                    for (int ni = 0; ni < 2; ++ni)
                        acc[mi][ni] = __builtin_amdgcn_mfma_f32_16x16x32_bf16(af[mi], bfr[ni], acc[mi][ni], 0, 0, 0);
            }
            #pragma unroll
            for (int mi = 0; mi < 2; ++mi)
                #pragma unroll
                for (int r = 0; r < 4; ++r) {
                    int i = wm * 32 + mi * 16 + quad * 4 + r;
                    float den = sm.c.dpart[0][i] + sm.c.dpart[1][i] + sm.c.dpart[2][i] +
                                sm.c.dpart[3][i] + sm.c.dpart[4][i] + sm.c.dpart[5][i] + 1e-12f;
                    float rden = 1.f / den;
                    #pragma unroll
                    for (int ni = 0; ni < 2; ++ni)
                        yb[(size_t)(c * 64 + i) * 768 + h * 64 + wn * 32 + ni * 16 + lr] = acc[mi][ni][r] * rden;
                }
        }
    }
    grid_sync(bar, 192);

    // ---------- Phase D: out = y @ Wo, exactly 192 64x64 tiles ----------
    {
        int nt = b % 12, mt = b / 12;
        gemm_inblk_splitk(sm.g, yb, Wo, out, mt * 64, nt * 64, nt * 64, 768, 768);
    }
}

extern "C" void kernel_launch(void* const* d_in, const int* in_sizes, int n_in,
                              void* d_out, int out_size, void* d_ws, size_t ws_size,
                              hipStream_t stream) {
    const float* hs = (const float*)d_in[0];
    const float* Wq = (const float*)d_in[1];
    const float* Wk = (const float*)d_in[2];
    const float* Wv = (const float*)d_in[3];
    const float* Wo = (const float*)d_in[4];
    float* out = (float*)d_out;
    float* ws  = (float*)d_ws;

    // Workspace layout (unchanged slots):
    float* qkv = ws;                                        // 1024*1152 floats
    float* yb  = ws + 1179648;                              // 1024*768
    unsigned short* St = (unsigned short*)(ws + 1966080);   // 12*16*64*288 ushorts (bf16)
    float* zb  = ws + 5320704;                              // 12*16*273
    int* bar   = (int*)(ws + 5373184);                      // 2 ints, grid-barrier state

    // Barrier state must be re-zeroed every launch (workspace is poisoned between iterations).
    hipMemsetAsync(bar, 0, 2 * sizeof(int), stream);
    based_mega<<<192, 512, 0, stream>>>(hs, Wq, Wk, Wv, Wo, out, qkv, yb, St, zb, bar);
}

// Round 2
// 134.876 us; speedup vs baseline: 2.1098x; 2.1098x over previous
//
#include <hip/hip_runtime.h>

#define C2 0.17677669529663687f  // 1/(4*sqrt(2))

typedef __attribute__((ext_vector_type(8))) short short8;
typedef __attribute__((ext_vector_type(8))) unsigned short ushort8;
typedef __attribute__((ext_vector_type(4))) float f32x4;

// fp32 -> bf16 round-to-nearest-even
__device__ __forceinline__ unsigned short f2bf(float x) {
    union { float f; unsigned u; } v; v.f = x;
    unsigned r = v.u + 0x7fffu + ((v.u >> 16) & 1u);
    return (unsigned short)(r >> 16);
}
__device__ __forceinline__ float bf2f(unsigned short u) {
    union { unsigned u; float f; } v; v.u = ((unsigned)u) << 16;
    return v.f;
}

// ---------------- in-block split-K MFMA GEMM ----------------
// 512 threads: group g = waves 0-3 / 4-7 each computes the same 64x64 tile over half of K
// (K=384, 12 BK=32 steps, register-prefetch double-buffered LDS, one barrier/step),
// then group 1 dumps its partial to LDS and group 0 adds + stores. No atomics, no memset.
__device__ __forceinline__ void gemm_inblk_splitk(
    const float* __restrict__ A, const float* __restrict__ W,
    float* __restrict__ out, int row0, int n0, int outcol0, int ldw, int outld)
{
    __shared__ unsigned short Al[2][2][64][40];   // [group][buf]
    __shared__ unsigned short Bl[2][2][64][40];
    __shared__ float red[64][65];
    const int tid = threadIdx.x;            // 0..511
    const int g = tid >> 8;                 // K-group
    const int t = tid & 255;
    const int lane = t & 63, wave4 = t >> 6;
    const int wm = wave4 & 1, wn = wave4 >> 1;
    const int quad = lane >> 4, lr = lane & 15;
    const int k0base = g * 384;

    f32x4 acc[2][2] = {{{0.f,0.f,0.f,0.f},{0.f,0.f,0.f,0.f}},
                       {{0.f,0.f,0.f,0.f},{0.f,0.f,0.f,0.f}}};

    float4 ra[2], rb[2];
    #pragma unroll
    for (int l = 0; l < 2; ++l) {
        int idx = t + l * 256;
        ra[l] = *(const float4*)&A[(size_t)(row0 + (idx >> 3)) * 768 + k0base + (idx & 7) * 4];
        rb[l] = *(const float4*)&W[(size_t)(k0base + (idx >> 4)) * ldw + n0 + (idx & 15) * 4];
    }
    #pragma unroll
    for (int l = 0; l < 2; ++l) {
        int idx = t + l * 256;
        *(ushort4*)&Al[g][0][idx >> 3][(idx & 7) * 4] =
            make_ushort4(f2bf(ra[l].x), f2bf(ra[l].y), f2bf(ra[l].z), f2bf(ra[l].w));
        int kr = idx >> 4, nq = (idx & 15) * 4;
        int col = (((kr >> 3) ^ ((idx & 15) >> 2)) << 3) | (kr & 7);
        Bl[g][0][nq + 0][col] = f2bf(rb[l].x);
        Bl[g][0][nq + 1][col] = f2bf(rb[l].y);
        Bl[g][0][nq + 2][col] = f2bf(rb[l].z);
        Bl[g][0][nq + 3][col] = f2bf(rb[l].w);
    }
    __syncthreads();

    const int ITER = 12;   // 384 / 32
    #pragma unroll
    for (int i = 0; i < ITER; ++i) {
        const int cur = i & 1, nxt = cur ^ 1;
        float4 na[2], nb[2];
        if (i + 1 < ITER) {
            int kn = k0base + (i + 1) * 32;
            #pragma unroll
            for (int l = 0; l < 2; ++l) {
                int idx = t + l * 256;
                na[l] = *(const float4*)&A[(size_t)(row0 + (idx >> 3)) * 768 + kn + (idx & 7) * 4];
                nb[l] = *(const float4*)&W[(size_t)(kn + (idx >> 4)) * ldw + n0 + (idx & 15) * 4];
            }
        }
        short8 af[2], bfr[2];
        #pragma unroll
        for (int mi = 0; mi < 2; ++mi)
            af[mi] = *(const short8*)&Al[g][cur][wm * 32 + mi * 16 + lr][quad << 3];
        #pragma unroll
        for (int ni = 0; ni < 2; ++ni) {
            int csw = quad ^ ((wn * 2 + ni) & 3);
            bfr[ni] = *(const short8*)&Bl[g][cur][wn * 32 + ni * 16 + lr][csw << 3];
        }
        #pragma unroll
        for (int mi = 0; mi < 2; ++mi)
            #pragma unroll
            for (int ni = 0; ni < 2; ++ni)
                acc[mi][ni] = __builtin_amdgcn_mfma_f32_16x16x32_bf16(af[mi], bfr[ni], acc[mi][ni], 0, 0, 0);
        if (i + 1 < ITER) {
            #pragma unroll
            for (int l = 0; l < 2; ++l) {
                int idx = t + l * 256;
                *(ushort4*)&Al[g][nxt][idx >> 3][(idx & 7) * 4] =
                    make_ushort4(f2bf(na[l].x), f2bf(na[l].y), f2bf(na[l].z), f2bf(na[l].w));
                int kr = idx >> 4, nq = (idx & 15) * 4;
                int col = (((kr >> 3) ^ ((idx & 15) >> 2)) << 3) | (kr & 7);
                Bl[g][nxt][nq + 0][col] = f2bf(nb[l].x);
                Bl[g][nxt][nq + 1][col] = f2bf(nb[l].y);
                Bl[g][nxt][nq + 2][col] = f2bf(nb[l].z);
                Bl[g][nxt][nq + 3][col] = f2bf(nb[l].w);
            }
        }
        __syncthreads();
    }
    if (g == 1) {
        #pragma unroll
        for (int mi = 0; mi < 2; ++mi)
            #pragma unroll
            for (int ni = 0; ni < 2; ++ni)
                #pragma unroll
                for (int r = 0; r < 4; ++r)
                    red[wm * 32 + mi * 16 + quad * 4 + r][wn * 32 + ni * 16 + lr] = acc[mi][ni][r];
    }
    __syncthreads();
    if (g == 0) {
        #pragma unroll
        for (int mi = 0; mi < 2; ++mi)
            #pragma unroll
            for (int ni = 0; ni < 2; ++ni)
                #pragma unroll
                for (int r = 0; r < 4; ++r) {
                    int rr = wm * 32 + mi * 16 + quad * 4 + r;
                    int cc = wn * 32 + ni * 16 + lr;
                    out[(size_t)(row0 + rr) * outld + outcol0 + cc] = acc[mi][ni][r] + red[rr][cc];
                }
    }
}

// qkv: hidden(1024x768) @ [Wq|Wk|Wv] -> qkv(1024x1152). grid (18,16) x 512
__global__ __launch_bounds__(512) void gemm_qkv_mfma(
    const float* __restrict__ H, const float* __restrict__ Wq,
    const float* __restrict__ Wk, const float* __restrict__ Wv,
    float* __restrict__ out)
{
    const int nt = blockIdx.x, mt = blockIdx.y;
    const float* W; int ldw, n0;
    if (nt < 3)      { W = Wq; ldw = 192; n0 = nt * 64; }
    else if (nt < 6) { W = Wk; ldw = 192; n0 = (nt - 3) * 64; }
    else             { W = Wv; ldw = 768; n0 = (nt - 6) * 64; }
    gemm_inblk_splitk(H, W, out, mt * 64, n0, nt * 64, ldw, 1152);
}

// wo: y(1024x768) @ Wo(768x768) -> out(1024x768). grid (12,16) x 512
__global__ __launch_bounds__(512) void gemm_wo_mfma(
    const float* __restrict__ Y, const float* __restrict__ Wo, float* __restrict__ out)
{
    const int nt = blockIdx.x, mt = blockIdx.y;
    gemm_inblk_splitk(Y, Wo, out, mt * 64, nt * 64, nt * 64, 768, 768);
}

// ---------------- per-chunk state via MFMA -> S_T bf16 ----------------
// S_T[h][c][d][n] (ld=288, bf16): A = [V^T|ones] (m=80pad: d, row 64 = ones for z),
// B = phiK (n=320pad: feature). grid (16,12) x 256.
// Pad columns n in [273,288) are ZEROED (chunk_out reads them as global B-fragments).
__global__ __launch_bounds__(256) void chunk_state_k(
    const float* __restrict__ qkv, unsigned short* __restrict__ St, float* __restrict__ z)
{
    const int c = blockIdx.x, h = blockIdx.y;
    __shared__ float Kc[64][17];
    __shared__ unsigned short Pk[320][72];
    __shared__ unsigned short Vt[80][72];
    const int tid = threadIdx.x;
    const int lane = tid & 63, wave = tid >> 6;
    const int quad = lane >> 4, lr = lane & 15;

    {
        int s = tid >> 2, f4 = (tid & 3) * 4;
        float4 kv = *(const float4*)&qkv[(size_t)(c * 64 + s) * 1152 + 192 + h * 16 + f4];
        Kc[s][f4 + 0] = kv.x; Kc[s][f4 + 1] = kv.y; Kc[s][f4 + 2] = kv.z; Kc[s][f4 + 3] = kv.w;
    }
    #pragma unroll
    for (int l = 0; l < 4; ++l) {
        int idx = tid + l * 256;
        int s = idx >> 4, d4 = (idx & 15) * 4;
        float4 vv = *(const float4*)&qkv[(size_t)(c * 64 + s) * 1152 + 384 + h * 64 + d4];
        Vt[d4 + 0][s] = f2bf(vv.x);
        Vt[d4 + 1][s] = f2bf(vv.y);
        Vt[d4 + 2][s] = f2bf(vv.z);
        Vt[d4 + 3][s] = f2bf(vv.w);
    }
    for (int idx = tid; idx < 16 * 72; idx += 256) {
        int rr = 64 + idx / 72, ss = idx % 72;
        Vt[rr][ss] = (rr == 64 && ss < 64) ? (unsigned short)0x3F80 : (unsigned short)0;
    }
    __syncthreads();
    for (int idx = tid; idx < 2880; idx += 256) {
        int n = idx / 9, s8 = (idx % 9) * 8;
        short8 v8;
        #pragma unroll
        for (int tt = 0; tt < 8; ++tt) {
            int s = s8 + tt;
            float ph = 0.f;
            if (s < 64 && n < 273) {
                if (n == 0) ph = 1.f;
                else if (n < 17) ph = Kc[s][n - 1] * 0.5f;
                else { int m = n - 17; ph = Kc[s][m >> 4] * Kc[s][m & 15] * C2; }
            }
            v8[tt] = (short)f2bf(ph);
        }
        *(short8*)&Pk[n][s8] = v8;
    }
    __syncthreads();

    f32x4 acc[5][5];
    #pragma unroll
    for (int a = 0; a < 5; ++a)
        #pragma unroll
        for (int b = 0; b < 5; ++b) acc[a][b] = (f32x4){0.f, 0.f, 0.f, 0.f};
    #pragma unroll
    for (int ks = 0; ks < 2; ++ks) {
        short8 af[5], bfr[5];
        #pragma unroll
        for (int mt = 0; mt < 5; ++mt)              // A side: d (Vt)
            af[mt] = *(const short8*)&Vt[mt * 16 + lr][ks * 32 + quad * 8];
        #pragma unroll
        for (int nt = 0; nt < 5; ++nt)              // B side: feature n (Pk)
            bfr[nt] = *(const short8*)&Pk[(wave * 5 + nt) * 16 + lr][ks * 32 + quad * 8];
        #pragma unroll
        for (int mt = 0; mt < 5; ++mt)
            #pragma unroll
            for (int nt = 0; nt < 5; ++nt)
                acc[mt][nt] = __builtin_amdgcn_mfma_f32_16x16x32_bf16(af[mt], bfr[nt], acc[mt][nt], 0, 0, 0);
    }
    unsigned short* Sbt = St + (size_t)(h * 16 + c) * 18432;
    float* zb = z + (h * 16 + c) * 273;
    #pragma unroll
    for (int nt = 0; nt < 5; ++nt) {
        int n = (wave * 5 + nt) * 16 + lr;
        if (n < 288) {
            #pragma unroll
            for (int mt = 0; mt < 4; ++mt)
                #pragma unroll
                for (int r = 0; r < 4; ++r)
                    Sbt[(mt * 16 + quad * 4 + r) * 288 + n] =
                        (n < 273) ? f2bf(acc[mt][nt][r]) : (unsigned short)0;
            if (quad == 0 && n < 273) zb[n] = acc[4][nt][0];   // d==64 ones-row -> z
        }
    }
}

// ---------------- exclusive prefix over 16 chunks (in place; S bf16, z fp32) ----------------
// Batched: all 16 chunk values loaded up-front (ushort8-vectorized), no dependent-load chain.
__global__ __launch_bounds__(256) void scan_state_k(unsigned short* __restrict__ St, float* __restrict__ z)
{
    const int NV = 12 * 64 * 36;   // 27,648 ushort8 chains (covers all 288 cols incl. zero pad)
    int gid = blockIdx.x * 256 + threadIdx.x;
    if (gid < NV) {
        int hh = gid / (64 * 36), rem = gid % (64 * 36);
        int d = rem / 36, nb = rem % 36;
        unsigned short* p = St + (size_t)hh * 16 * 18432 + d * 288 + nb * 8;
        ushort8 v[16];
        #pragma unroll
        for (int cc = 0; cc < 16; ++cc) v[cc] = *(const ushort8*)(p + (size_t)cc * 18432);
        float run[8] = {0.f,0.f,0.f,0.f,0.f,0.f,0.f,0.f};
        #pragma unroll
        for (int cc = 0; cc < 16; ++cc) {
            ushort8 w;
            #pragma unroll
            for (int j = 0; j < 8; ++j) {
                w[j] = f2bf(run[j]);
                run[j] += bf2f(v[cc][j]);
            }
            *(ushort8*)(p + (size_t)cc * 18432) = w;
        }
    } else if (gid < NV + 12 * 273) {
        int e2 = gid - NV, hh = e2 / 273, n = e2 % 273;
        float* p = z + hh * 16 * 273 + n;
        float v[16];
        #pragma unroll
        for (int cc = 0; cc < 16; ++cc) v[cc] = p[cc * 273];
        float run = 0.f;
        #pragma unroll
        for (int cc = 0; cc < 16; ++cc) { p[cc * 273] = run; run += v[cc]; }
    }
}

// ---------------- per-chunk output via ONE fused MFMA GEMM ----------------
// Slim LDS (72.5 KB -> 2 blocks/CU): the 46 KB Sv staging buffer is gone. State B-fragments
// (k-steps 0..8) are loaded directly from global S_T into registers at kernel entry — S_T's
// [d][n] global layout IS the B-fragment layout, and the load latency hides under staging +
// feature computation + QK^T. V (k-steps 9,10) keeps a small 9 KB LDS buffer.
__global__ __launch_bounds__(256) void chunk_out_k(
    const float* __restrict__ qkv, const unsigned short* __restrict__ St, const float* __restrict__ z,
    float* __restrict__ y)
{
    const int c = blockIdx.x, h = blockIdx.y;
    __shared__ float Qc[64][17];
    __shared__ unsigned short Aq[64][40];
    __shared__ unsigned short Kb[64][40];
    __shared__ unsigned short Pq[64][360];
    __shared__ unsigned short Vt[64][72];
    __shared__ float zl[288];
    __shared__ float dpart[6][64];
    const int tid = threadIdx.x;
    const int lane = tid & 63, wave = tid >> 6;
    const int wm = wave & 1, wn = wave >> 1;
    const int quad = lane >> 4, lr = lane & 15;

    // State B-fragments: issue all 18 global loads first; used only in the final GEMM.
    const unsigned short* Sgt = St + (size_t)(h * 16 + c) * 18432;
    short8 sfr[2][9];
    #pragma unroll
    for (int ni = 0; ni < 2; ++ni)
        #pragma unroll
        for (int ks = 0; ks < 9; ++ks)
            sfr[ni][ks] = *(const short8*)&Sgt[(wn * 32 + ni * 16 + lr) * 288 + ks * 32 + quad * 8];

    {
        int s = tid >> 2, f4 = (tid & 3) * 4;
        const float* base = &qkv[(size_t)(c * 64 + s) * 1152 + h * 16];
        float4 qv = *(const float4*)&base[f4];
        float4 kv = *(const float4*)&base[192 + f4];
        Qc[s][f4 + 0] = qv.x; Qc[s][f4 + 1] = qv.y; Qc[s][f4 + 2] = qv.z; Qc[s][f4 + 3] = qv.w;
        *(ushort4*)&Aq[s][f4] = make_ushort4(f2bf(qv.x), f2bf(qv.y), f2bf(qv.z), f2bf(qv.w));
        *(ushort4*)&Kb[s][f4] = make_ushort4(f2bf(kv.x), f2bf(kv.y), f2bf(kv.z), f2bf(kv.w));
        *(ushort4*)&Aq[s][16 + (tid & 3) * 4] = make_ushort4(0, 0, 0, 0);
        *(ushort4*)&Kb[s][16 + (tid & 3) * 4] = make_ushort4(0, 0, 0, 0);
    }
    #pragma unroll
    for (int l = 0; l < 4; ++l) {                    // V -> Vt[d][s]
        int idx = tid + l * 256;
        int ss = idx >> 4, d4 = (idx & 15) * 4;
        float4 vv = *(const float4*)&qkv[(size_t)(c * 64 + ss) * 1152 + 384 + h * 64 + d4];
        Vt[d4 + 0][ss] = f2bf(vv.x);
        Vt[d4 + 1][ss] = f2bf(vv.y);
        Vt[d4 + 2][ss] = f2bf(vv.z);
        Vt[d4 + 3][ss] = f2bf(vv.w);
    }
    const float* zg = z + (h * 16 + c) * 273;
    for (int idx = tid; idx < 288; idx += 256) zl[idx] = (idx < 273) ? zg[idx] : 0.f;
    __syncthreads();

    f32x4 accS[2][2] = {{{0.f,0.f,0.f,0.f},{0.f,0.f,0.f,0.f}},
                        {{0.f,0.f,0.f,0.f},{0.f,0.f,0.f,0.f}}};
    {
        short8 af[2], bfr[2];
        #pragma unroll
        for (int mi = 0; mi < 2; ++mi)
            af[mi] = *(const short8*)&Aq[wm * 32 + mi * 16 + lr][quad * 8];
        #pragma unroll
        for (int ni = 0; ni < 2; ++ni)
            bfr[ni] = *(const short8*)&Kb[wn * 32 + ni * 16 + lr][quad * 8];
        #pragma unroll
        for (int mi = 0; mi < 2; ++mi)
            #pragma unroll
            for (int ni = 0; ni < 2; ++ni)
                accS[mi][ni] = __builtin_amdgcn_mfma_f32_16x16x32_bf16(af[mi], bfr[ni], accS[mi][ni], 0, 0, 0);
    }

    {
        int i = lane;
        float qr[16];
        #pragma unroll
        for (int f = 0; f < 16; ++f) qr[f] = Qc[i][f];
        float dp = 0.f;
        int n0 = wave * 72;
        for (int n = n0; n < n0 + 72; ++n) {
            float ph;
            if (n == 0) ph = 1.f;
            else if (n < 17) ph = qr[n - 1] * 0.5f;
            else if (n < 273) { int m = n - 17; ph = qr[m >> 4] * qr[m & 15] * C2; }
            else ph = 0.f;
            Pq[i][n] = f2bf(ph);
            dp += ph * zl[n];
        }
        dpart[wave][i] = dp;
    }

    #pragma unroll
    for (int mi = 0; mi < 2; ++mi) {
        float rs[4] = {0.f, 0.f, 0.f, 0.f};
        #pragma unroll
        for (int ni = 0; ni < 2; ++ni)
            #pragma unroll
            for (int r = 0; r < 4; ++r) {
                int i = wm * 32 + mi * 16 + quad * 4 + r;
                int j = wn * 32 + ni * 16 + lr;
                float u = accS[mi][ni][r];
                float sc = (j <= i) ? (1.f + 0.25f * u + u * u * (1.f / 32.f)) : 0.f;
                rs[r] += sc;
                Pq[i][288 + j] = f2bf(sc);
            }
        #pragma unroll
        for (int r = 0; r < 4; ++r) {
            float v = rs[r];
            v += __shfl_xor(v, 1);
            v += __shfl_xor(v, 2);
            v += __shfl_xor(v, 4);
            v += __shfl_xor(v, 8);
            if (lr == 0) dpart[4 + wn][wm * 32 + mi * 16 + quad * 4 + r] = v;
        }
    }
    __syncthreads();

    f32x4 acc[2][2] = {{{0.f,0.f,0.f,0.f},{0.f,0.f,0.f,0.f}},
                       {{0.f,0.f,0.f,0.f},{0.f,0.f,0.f,0.f}}};
    #pragma unroll
    for (int ks = 0; ks < 11; ++ks) {
        short8 af[2], bfr[2];
        #pragma unroll
        for (int mi = 0; mi < 2; ++mi)
            af[mi] = *(const short8*)&Pq[wm * 32 + mi * 16 + lr][ks * 32 + quad * 8];
        #pragma unroll
        for (int ni = 0; ni < 2; ++ni)
            bfr[ni] = (ks < 9)
                ? sfr[ni][ks]
                : *(const short8*)&Vt[wn * 32 + ni * 16 + lr][(ks - 9) * 32 + quad * 8];
        #pragma unroll
        for (int mi = 0; mi < 2; ++mi)
            #pragma unroll
            for (int ni = 0; ni < 2; ++ni)
                acc[mi][ni] = __builtin_amdgcn_mfma_f32_16x16x32_bf16(af[mi], bfr[ni], acc[mi][ni], 0, 0, 0);
    }

    #pragma unroll
    for (int mi = 0; mi < 2; ++mi)
        #pragma unroll
        for (int r = 0; r < 4; ++r) {
            int i = wm * 32 + mi * 16 + quad * 4 + r;
            float den = dpart[0][i] + dpart[1][i] + dpart[2][i] +
                        dpart[3][i] + dpart[4][i] + dpart[5][i] + 1e-12f;
            float rden = 1.f / den;
            #pragma unroll
            for (int ni = 0; ni < 2; ++ni)
                y[(size_t)(c * 64 + i) * 768 + h * 64 + wn * 32 + ni * 16 + lr] = acc[mi][ni][r] * rden;
        }
}

extern "C" void kernel_launch(void* const* d_in, const int* in_sizes, int n_in,
                              void* d_out, int out_size, void* d_ws, size_t ws_size,
                              hipStream_t stream) {
    const float* hs = (const float*)d_in[0];
    const float* Wq = (const float*)d_in[1];
    const float* Wk = (const float*)d_in[2];
    const float* Wv = (const float*)d_in[3];
    const float* Wo = (const float*)d_in[4];
    float* out = (float*)d_out;
    float* ws  = (float*)d_ws;

    // Workspace layout (unchanged): St is bf16 S_T[12*16][64][288] inside the old Sb slot.
    float* qkv = ws;                                        // 1024*1152 floats
    float* yb  = ws + 1179648;                              // 1024*768
    unsigned short* St = (unsigned short*)(ws + 1966080);   // 12*16*64*288 ushorts
    float* zb  = ws + 5320704;                              // 12*16*273

    gemm_qkv_mfma<<<dim3(18, 16), 512, 0, stream>>>(hs, Wq, Wk, Wv, qkv);
    chunk_state_k<<<dim3(16, 12), 256, 0, stream>>>(qkv, St, zb);
    scan_state_k <<<121, 256, 0, stream>>>(St, zb);
    chunk_out_k  <<<dim3(16, 12), 256, 0, stream>>>(qkv, St, zb, yb);
    gemm_wo_mfma <<<dim3(12, 16), 512, 0, stream>>>(yb, Wo, out);
}